// Round 3
// baseline (185.943 us; speedup 1.0000x reference)
//
#include <hip/hip_runtime.h>
#include <hip/hip_bf16.h>
#include <type_traits>

// out[b] = X[b] @ (X[b]^T @ X[b]);  B=8, S=4096, D=512, fp32 in/out.
// Pipeline (bf16 MFMA, fp32 accumulate), ws = 268MB observed:
//   k1: Xt[d][s] bf16 -> d_out[0:33.5M) ; Xb16[s][d] bf16 (A-tile-swizzled
//       octet order, see below) -> ws+4.2M
//   k2: split-K=8 gram partials bf16, upper-triangle tiles only (symmetry),
//       XCD-swizzled, LDS dbuf -> ws+37.7M
//   kr: reduce 8 bf16 partials (triangle) -> full bf16 gram via LDS-transpose
//       mirror -> ws[0:4.2M)
//   k3: out = Xb16 . gram^T. Rebuilt: BK=64 (8 barriers not 16), B-frags
//       direct from global (gram is L2-resident; no Bs LDS), A-tile XOR-
//       swizzled via pre-swizzled global source (m173 pattern) so the
//       128B-row ds_read_b128 is 2-way (free) instead of 16-way.

typedef __attribute__((ext_vector_type(8))) short short8;
typedef __attribute__((ext_vector_type(4))) float floatx4;

#define BM 128
#define BN 128
#define BK 32

#define BATCH 8
#define SEQ 4096
#define DIM 512
#define SPLITK 8

__device__ __forceinline__ void async_copy16(const __hip_bfloat16* g, __hip_bfloat16* l) {
  __builtin_amdgcn_global_load_lds((const __attribute__((address_space(1))) void*)g,
                                   (__attribute__((address_space(3))) void*)l, 16, 0, 0);
}

// Upper-triangle tile map: t in [0,10) -> (ti<=tj) of a 4x4 tile grid.
__device__ __forceinline__ void tri_map(int t, int& ti, int& tj) {
  if (t < 4)      { ti = 0; tj = t; }
  else if (t < 7) { ti = 1; tj = t - 3; }
  else if (t < 9) { ti = 2; tj = t - 5; }
  else            { ti = 3; tj = 3; }
}

// ---------------- k1: transpose+cast (Xt) and swizzled straight cast (Xb16) -
// Xb16 octet swizzle: within each 64-d block, the 8-element octet at index dc
// is stored at octet dc ^ (s&7). k3 stages 64-d windows linearly into LDS
// rows of 128B; reading octet (k8 ^ (row&7)) there recovers element k8 while
// spreading the 16 r16-lanes of a ds_read_b128 across 8 bank phases.
__global__ __launch_bounds__(256) void transpose_cast_kernel(
    const float* __restrict__ X, __hip_bfloat16* __restrict__ Xt,
    __hip_bfloat16* __restrict__ Xb16) {
  __shared__ float tile[64][65];
  const int b = blockIdx.z;
  const int s0 = blockIdx.x * 64;
  const int d0 = blockIdx.y * 64;
  const int tid = threadIdx.x;
  const float* Xb = X + (long)b * SEQ * DIM;
  __hip_bfloat16* Xtb = Xt + (long)b * DIM * SEQ;
  // float4-vectorized tile fill.
  {
    const int c4 = (tid & 15) * 4;
    const int r0 = tid >> 4;  // 0..15
#pragma unroll
    for (int r = 0; r < 64; r += 16) {
      const float4 v = *(const float4*)&Xb[(long)(s0 + r + r0) * DIM + d0 + c4];
      tile[r + r0][c4 + 0] = v.x;
      tile[r + r0][c4 + 1] = v.y;
      tile[r + r0][c4 + 2] = v.z;
      tile[r + r0][c4 + 3] = v.w;
    }
  }
  __syncthreads();
  // Xt[d][s]: pack 8 consecutive s per 16B store.
#pragma unroll
  for (int it = 0; it < 2; ++it) {
    const int idx = it * 256 + tid;    // 0..511
    const int dl = idx >> 3;           // 0..63
    const int so = (idx & 7) * 8;      // 0,8,..,56
    union { short8 v; __hip_bfloat16 e[8]; } u;
#pragma unroll
    for (int j = 0; j < 8; ++j) u.e[j] = __float2bfloat16(tile[so + j][dl]);
    *(short8*)&Xtb[(long)(d0 + dl) * SEQ + s0 + so] = u.v;
  }
  // Xb16[s][d]: straight cast, octet-swizzled within the 64-d block.
  if (Xb16 != nullptr) {
    __hip_bfloat16* Xcb = Xb16 + (long)b * SEQ * DIM;
#pragma unroll
    for (int it = 0; it < 2; ++it) {
      const int idx = it * 256 + tid;  // 0..511
      const int sl = idx >> 3;         // 0..63
      const int dc = idx & 7;          // source 8-wide d chunk
      const int dcs = dc ^ (sl & 7);   // swizzled destination octet
      union { short8 v; __hip_bfloat16 e[8]; } u;
#pragma unroll
      for (int j = 0; j < 8; ++j) u.e[j] = __float2bfloat16(tile[sl][dc * 8 + j]);
      *(short8*)&Xcb[(long)(s0 + sl) * DIM + d0 + dcs * 8] = u.v;
    }
  }
}

// ---------------- GEMM: C = A . Bt^T (Bt stored [N][K], K-contiguous) -------
// (used for k2 and the no-workspace k3 fallback; unchanged structure)
template <int NSPLIT, bool AFP32, int SWZ, typename CT>
__global__ __launch_bounds__(256, 4) void gemm_bt_kernel(
    const float* __restrict__ Af, const __hip_bfloat16* __restrict__ Ab,
    const __hip_bfloat16* __restrict__ Bt, CT* __restrict__ C,
    int K, int lda, int ldb, int ldc, long strideA, long strideB, long strideC) {
  __shared__ __align__(16) __hip_bfloat16 As[2][BM * BK];  // [m][k]
  __shared__ __align__(16) __hip_bfloat16 Bs[2][BN * BK];  // [n][k]

  int bz, m0, n0;
  if constexpr (SWZ == 1) {
    const int lin = blockIdx.x;        // 0..127 per batch
    bz = blockIdx.z;
    const int xcd = lin & 7;
    const int t = lin >> 3;            // 0..15
    n0 = (t & 3) * BN;
    m0 = ((t >> 2) * 8 + xcd) * BM;
  } else if constexpr (SWZ == 2) {
    bz = blockIdx.x;                   // chunk id, fastest dim -> xcd = bz & 7
    int ti, tj;
    tri_map(blockIdx.y, ti, tj);       // upper triangle only
    m0 = ti * BM;
    n0 = tj * BN;
  } else {
    bz = blockIdx.z;
    m0 = blockIdx.y * BM;
    n0 = blockIdx.x * BN;
  }
  const int b = bz / NSPLIT;
  const int split = bz % NSPLIT;
  const int klen = K / NSPLIT;
  const int kb = split * klen;

  const int tid = threadIdx.x;
  const int w = tid >> 6;
  const int lane = tid & 63;
  const int r16 = lane & 15;
  const int kg = lane >> 4;
  const int wr = w >> 1;
  const int wc = w & 1;

  const float* Afb = AFP32 ? Af + b * strideA : nullptr;
  const __hip_bfloat16* Abb = AFP32 ? nullptr : Ab + b * strideA;
  const __hip_bfloat16* Btb = Bt + b * strideB;
  CT* Cb = C + (long)bz * strideC;

  const floatx4 vzero = {0.f, 0.f, 0.f, 0.f};
  floatx4 acc[4][4];
#pragma unroll
  for (int i = 0; i < 4; ++i)
#pragma unroll
    for (int j = 0; j < 4; ++j) acc[i][j] = vzero;

  const int arow = tid >> 1;
  const int ahalf = tid & 1;
  float f[16];

  auto stageB = [&](int buf, int k0) {
#pragma unroll
    for (int q = 0; q < 2; ++q) {
      const __hip_bfloat16* gb =
          Btb + (long)(n0 + w * 32 + q * 16 + (lane >> 2)) * ldb + k0 + (lane & 3) * 8;
      async_copy16(gb, &Bs[buf][(w * 32 + q * 16) * BK]);
    }
  };
  auto stageA = [&](int buf, int k0) {
#pragma unroll
    for (int q = 0; q < 2; ++q) {
      const __hip_bfloat16* ga =
          Abb + (long)(m0 + w * 32 + q * 16 + (lane >> 2)) * lda + k0 + (lane & 3) * 8;
      async_copy16(ga, &As[buf][(w * 32 + q * 16) * BK]);
    }
  };
  auto loadF = [&](int k0) {
    const float* ar = Afb + (long)(m0 + arow) * lda + k0 + ahalf * 16;
    *(float4*)(f + 0)  = *(const float4*)(ar + 0);
    *(float4*)(f + 4)  = *(const float4*)(ar + 4);
    *(float4*)(f + 8)  = *(const float4*)(ar + 8);
    *(float4*)(f + 12) = *(const float4*)(ar + 12);
  };
  auto writeF = [&](int buf) {
    union { short8 v[2]; __hip_bfloat16 e[16]; } u;
#pragma unroll
    for (int t = 0; t < 16; ++t) u.e[t] = __float2bfloat16(f[t]);
    short8* dst = (short8*)&As[buf][arow * BK + ahalf * 16];
    dst[0] = u.v[0];
    dst[1] = u.v[1];
  };

  const int nIter = klen / BK;
  if constexpr (AFP32) {
    loadF(kb);
    writeF(0);
    loadF(kb + BK);
  } else {
    stageA(0, kb);
  }
  stageB(0, kb);

  for (int t = 0; t < nIter; ++t) {
    const int cur = t & 1;
    __syncthreads();
    if (t + 1 < nIter) {
      if constexpr (AFP32) {
        writeF(cur ^ 1);
        if (t + 2 < nIter) loadF(kb + (t + 2) * BK);
      } else {
        stageA(cur ^ 1, kb + (t + 1) * BK);
      }
      stageB(cur ^ 1, kb + (t + 1) * BK);
    }

    short8 a[4], bfrag[4];
#pragma unroll
    for (int i = 0; i < 4; ++i)
      a[i] = *(const short8*)&As[cur][(wr * 64 + i * 16 + r16) * BK + kg * 8];
#pragma unroll
    for (int j = 0; j < 4; ++j)
      bfrag[j] = *(const short8*)&Bs[cur][(wc * 64 + j * 16 + r16) * BK + kg * 8];
#pragma unroll
    for (int i = 0; i < 4; ++i)
#pragma unroll
      for (int j = 0; j < 4; ++j)
        acc[i][j] = __builtin_amdgcn_mfma_f32_16x16x32_bf16(a[i], bfrag[j], acc[i][j], 0, 0, 0);
  }

#pragma unroll
  for (int i = 0; i < 4; ++i) {
    const int row_base = m0 + wr * 64 + i * 16 + kg * 4;
#pragma unroll
    for (int j = 0; j < 4; ++j) {
      const int col = n0 + wc * 64 + j * 16 + r16;
#pragma unroll
      for (int r = 0; r < 4; ++r) {
        const float v = acc[i][j][r];
        if constexpr (std::is_same<CT, float>::value)
          Cb[(long)(row_base + r) * ldc + col] = v;
        else
          Cb[(long)(row_base + r) * ldc + col] = __float2bfloat16(v);
      }
    }
  }
}

// ---------------- k3 fast path: out = Xb16 . gram^T ------------------------
// BK=64: 8 iterations, one barrier each (halved vs BK=32). As only in LDS
// (32KB total -> 4 blocks/CU); B-fragments load directly from gram in global
// (512KB/batch, L2-resident, read by 128 blocks). A-tile rows are 128B; the
// octet swizzle written by k1 makes the ds_read_b128 per-16-lane-group hit 8
// distinct bank phases (2-way = free) instead of all-same-phase (16-way).
// Accumulation order (k-octets 0..7 per 64-window, windows in order) is
// identical to the BK=32 version -> bit-identical output.
__global__ __launch_bounds__(256, 4) void gemm_xg_kernel(
    const __hip_bfloat16* __restrict__ Xs,  // swizzled Xb16 [B][S][D]
    const __hip_bfloat16* __restrict__ G,   // gram [B][D][D] (bf16)
    float* __restrict__ C) {
  __shared__ __align__(16) __hip_bfloat16 As[2][BM * 64];  // 16KB x2

  const int lin = blockIdx.x;  // 0..127 per batch, XCD-swizzled
  const int b = blockIdx.z;
  const int xcd = lin & 7;
  const int t8 = lin >> 3;     // 0..15
  const int n0 = (t8 & 3) * BN;
  const int m0 = ((t8 >> 2) * 8 + xcd) * BM;

  const int tid = threadIdx.x;
  const int w = tid >> 6;
  const int lane = tid & 63;
  const int r16 = lane & 15;
  const int kg = lane >> 4;
  const int wr = w >> 1;
  const int wc = w & 1;
  const int ph = r16 & 7;      // bank-phase for the A-octet swizzle

  const __hip_bfloat16* Xb = Xs + (long)b * SEQ * DIM;
  const __hip_bfloat16* Gb = G + (long)b * DIM * DIM;
  float* Cb = C + (long)b * SEQ * DIM;

  const floatx4 vzero = {0.f, 0.f, 0.f, 0.f};
  floatx4 acc[4][4];
#pragma unroll
  for (int i = 0; i < 4; ++i)
#pragma unroll
    for (int j = 0; j < 4; ++j) acc[i][j] = vzero;

  // Stage one 128x64 A-tile (16KB): 4 passes x (256 threads x 16B).
  // Wave-uniform LDS base + lane*16: lane L covers row w*8+(L>>3), octet L&7.
  auto stageA = [&](int buf, int k0) {
#pragma unroll
    for (int q = 0; q < 4; ++q) {
      const int row = q * 32 + w * 8 + (lane >> 3);
      const __hip_bfloat16* g = Xb + (long)(m0 + row) * DIM + k0 + (lane & 7) * 8;
      async_copy16(g, &As[buf][(q * 32 + w * 8) * 64]);
    }
  };

  stageA(0, 0);

  const int nIter = DIM / 64;  // 8
  for (int t = 0; t < nIter; ++t) {
    const int cur = t & 1;
    __syncthreads();  // drains vmcnt: buffer `cur` ready; prior reads of cur^1 done
    if (t + 1 < nIter) stageA(cur ^ 1, (t + 1) * 64);
    const int k0 = t * 64;

#pragma unroll
    for (int ks = 0; ks < 2; ++ks) {
      short8 bfrag[4];
#pragma unroll
      for (int j = 0; j < 4; ++j)
        bfrag[j] = *(const short8*)&Gb[(long)(n0 + wc * 64 + j * 16 + r16) * DIM +
                                       k0 + ks * 32 + kg * 8];
      short8 a[4];
#pragma unroll
      for (int i = 0; i < 4; ++i)
        a[i] = *(const short8*)&As[cur][(wr * 64 + i * 16 + r16) * 64 +
                                        (((ks * 4 + kg) ^ ph) * 8)];
#pragma unroll
      for (int i = 0; i < 4; ++i)
#pragma unroll
        for (int j = 0; j < 4; ++j)
          acc[i][j] = __builtin_amdgcn_mfma_f32_16x16x32_bf16(a[i], bfrag[j], acc[i][j], 0, 0, 0);
    }
  }

  // epilogue: row = kg*4 + r, col = r16 (m89-verified C/D map)
#pragma unroll
  for (int i = 0; i < 4; ++i) {
    const int row_base = m0 + wr * 64 + i * 16 + kg * 4;
#pragma unroll
    for (int j = 0; j < 4; ++j) {
      const int col = n0 + wc * 64 + j * 16 + r16;
#pragma unroll
      for (int r = 0; r < 4; ++r)
        Cb[(long)(row_base + r) * DIM + col] = acc[i][j][r];
    }
  }
}

// ---------------- kr: reduce NSPLIT partials (triangle) -> full gram --------
template <int NSPLIT>
__global__ __launch_bounds__(256) void reduce_mirror_kernel(
    const __hip_bfloat16* __restrict__ P, __hip_bfloat16* __restrict__ G) {
  __shared__ float tile[64][65];
  int ti, tj;
  tri_map(blockIdx.x, ti, tj);
  const int b = blockIdx.y;
  const __hip_bfloat16* Pb = P + (long)b * NSPLIT * DIM * DIM;
  __hip_bfloat16* Gb = G + (long)b * DIM * DIM;
  const int r0 = ti * 128, c0 = tj * 128;
  const int tid = threadIdx.x;
  const int lrow = tid >> 3;        // 0..31
  const int lcol = (tid & 7) * 8;   // 0..56

#pragma unroll
  for (int q = 0; q < 4; ++q) {
    const int qr = (q >> 1) * 64, qc = (q & 1) * 64;
    float s[2][8];
#pragma unroll
    for (int h = 0; h < 2; ++h) {
      const int row = lrow + h * 32;
#pragma unroll
      for (int j = 0; j < 8; ++j) s[h][j] = 0.f;
#pragma unroll
      for (int p = 0; p < NSPLIT; ++p) {
        union { short8 v; __hip_bfloat16 e8[8]; } u;
        u.v = *(const short8*)&Pb[(long)p * DIM * DIM +
                                  (long)(r0 + qr + row) * DIM + c0 + qc + lcol];
#pragma unroll
        for (int j = 0; j < 8; ++j) s[h][j] += __bfloat162float(u.e8[j]);
      }
      union { short8 v; __hip_bfloat16 e8[8]; } o;
#pragma unroll
      for (int j = 0; j < 8; ++j) o.e8[j] = __float2bfloat16(s[h][j]);
      *(short8*)&Gb[(long)(r0 + qr + row) * DIM + c0 + qc + lcol] = o.v;
    }
    if (ti != tj) {
      if (q) __syncthreads();
#pragma unroll
      for (int h = 0; h < 2; ++h) {
        const int row = lrow + h * 32;
#pragma unroll
        for (int j = 0; j < 8; ++j) tile[row][lcol + j] = s[h][j];
      }
      __syncthreads();
#pragma unroll
      for (int it = 0; it < 2; ++it) {
        const int idx = it * 256 + tid;
        const int dl = idx >> 3;
        const int so = (idx & 7) * 8;
        union { short8 v; __hip_bfloat16 e8[8]; } o;
#pragma unroll
        for (int j = 0; j < 8; ++j) o.e8[j] = __float2bfloat16(tile[so + j][dl]);
        *(short8*)&Gb[(long)(c0 + qc + dl) * DIM + r0 + qr + so] = o.v;
      }
    }
  }
}

// ---------------- host launch ----------------------------------------------
extern "C" void kernel_launch(void* const* d_in, const int* in_sizes, int n_in,
                              void* d_out, int out_size, void* d_ws, size_t ws_size,
                              hipStream_t stream) {
  const float* X = (const float*)d_in[0];
  float* out = (float*)d_out;
  const long xtBytes = (long)BATCH * DIM * SEQ * 2;               // 33.5 MB
  const long gramBytes = (long)BATCH * DIM * DIM * 2;             // 4.2 MB
  const long partBytes = (long)BATCH * SPLITK * DIM * DIM * 2;    // 33.5 MB (bf16)
  __hip_bfloat16* Xt = (__hip_bfloat16*)d_out;
  __hip_bfloat16* gram = (__hip_bfloat16*)d_ws;

  const bool bigWs = ws_size >= (size_t)(gramBytes + xtBytes + partBytes);
  const bool midWs = ws_size >= (size_t)(gramBytes + xtBytes);
  __hip_bfloat16* Xb16 = midWs ? (__hip_bfloat16*)((char*)d_ws + gramBytes) : nullptr;

  // k1: Xt[b][d][s] (+ swizzled Xb16[b][s][d] if ws fits)
  transpose_cast_kernel<<<dim3(SEQ / 64, DIM / 64, BATCH), 256, 0, stream>>>(X, Xt, Xb16);

  // k2: split-8 gram partials (bf16), upper-triangle tiles only (symmetry)
  __hip_bfloat16* partials = bigWs
      ? (__hip_bfloat16*)((char*)d_ws + gramBytes + xtBytes)
      : (__hip_bfloat16*)((char*)d_out + xtBytes);
  gemm_bt_kernel<SPLITK, false, 2, __hip_bfloat16>
      <<<dim3(BATCH * SPLITK, 10, 1), 256, 0, stream>>>(
          nullptr, Xt, Xt, partials, SEQ, SEQ, SEQ, DIM,
          (long)DIM * SEQ, (long)DIM * SEQ, (long)DIM * DIM);

  // kr: triangle partials -> full gram (mirror off-diagonal tiles)
  reduce_mirror_kernel<SPLITK><<<dim3(10, BATCH), 256, 0, stream>>>(partials, gram);

  // k3: out = Xb16 . gram^T (M=4096, N=512, K=512)
  if (midWs) {
    gemm_xg_kernel<<<dim3(128, 1, BATCH), 256, 0, stream>>>(Xb16, gram, out);
  } else {
    gemm_bt_kernel<1, true, 1, float><<<dim3(128, 1, BATCH), 256, 0, stream>>>(
        X, nullptr, gram, out, DIM, DIM, DIM, DIM,
        (long)SEQ * DIM, (long)DIM * DIM, (long)SEQ * DIM);
  }
}

// Round 4
// 163.214 us; speedup vs baseline: 1.1393x; 1.1393x over previous
//
#include <hip/hip_runtime.h>
#include <hip/hip_bf16.h>
#include <type_traits>

// out[b] = X[b] @ (X[b]^T @ X[b]);  B=8, S=4096, D=512, fp32 in/out.
// Pipeline (bf16 MFMA, fp32 accumulate), ws = 268MB observed:
//   k1: Xt[d][s] bf16 -> d_out[0:33.5M) ; Xb16[s][d] bf16 (octet-swizzled
//       per 64-d window: oct ^= s&7) -> ws+4.2M
//   k2: split-K=8 gram partials bf16, upper-triangle tiles only (symmetry),
//       XCD-swizzled, LDS dbuf (proven 2-phase gemm_bt) -> ws+37.7M
//   kr: reduce 8 bf16 partials -> full bf16 gram via LDS-transpose mirror;
//       gram stored octet-swizzled (oct ^= row&7 per 64-col window) for k3.
//   k3: 8-phase 256^2 deep-pipelined GEMM (T3+T4 counted vmcnt, T5 setprio,
//       octet-XOR conflict-free LDS via pre-swizzled global content).
//       512 thr, 8 waves (2M x 4N), BK=64, 128KB LDS, 1 block/CU,
//       grid 256 = 8 XCD x (one batch per XCD, 32 tiles).

typedef __attribute__((ext_vector_type(8))) short short8;
typedef __attribute__((ext_vector_type(4))) float floatx4;

#define BM 128
#define BN 128
#define BK 32

#define BATCH 8
#define SEQ 4096
#define DIM 512
#define SPLITK 8

__device__ __forceinline__ void async_copy16(const __hip_bfloat16* g, __hip_bfloat16* l) {
  __builtin_amdgcn_global_load_lds((const __attribute__((address_space(1))) void*)g,
                                   (__attribute__((address_space(3))) void*)l, 16, 0, 0);
}

// Upper-triangle tile map: t in [0,10) -> (ti<=tj) of a 4x4 tile grid.
__device__ __forceinline__ void tri_map(int t, int& ti, int& tj) {
  if (t < 4)      { ti = 0; tj = t; }
  else if (t < 7) { ti = 1; tj = t - 3; }
  else if (t < 9) { ti = 2; tj = t - 5; }
  else            { ti = 3; tj = 3; }
}

// ---------------- k1: transpose+cast (Xt) and swizzled straight cast (Xb16) -
__global__ __launch_bounds__(256) void transpose_cast_kernel(
    const float* __restrict__ X, __hip_bfloat16* __restrict__ Xt,
    __hip_bfloat16* __restrict__ Xb16) {
  __shared__ float tile[64][65];
  const int b = blockIdx.z;
  const int s0 = blockIdx.x * 64;
  const int d0 = blockIdx.y * 64;
  const int tid = threadIdx.x;
  const float* Xb = X + (long)b * SEQ * DIM;
  __hip_bfloat16* Xtb = Xt + (long)b * DIM * SEQ;
  {
    const int c4 = (tid & 15) * 4;
    const int r0 = tid >> 4;  // 0..15
#pragma unroll
    for (int r = 0; r < 64; r += 16) {
      const float4 v = *(const float4*)&Xb[(long)(s0 + r + r0) * DIM + d0 + c4];
      tile[r + r0][c4 + 0] = v.x;
      tile[r + r0][c4 + 1] = v.y;
      tile[r + r0][c4 + 2] = v.z;
      tile[r + r0][c4 + 3] = v.w;
    }
  }
  __syncthreads();
  // Xt[d][s]: pack 8 consecutive s per 16B store.
#pragma unroll
  for (int it = 0; it < 2; ++it) {
    const int idx = it * 256 + tid;    // 0..511
    const int dl = idx >> 3;           // 0..63
    const int so = (idx & 7) * 8;      // 0,8,..,56
    union { short8 v; __hip_bfloat16 e[8]; } u;
#pragma unroll
    for (int j = 0; j < 8; ++j) u.e[j] = __float2bfloat16(tile[so + j][dl]);
    *(short8*)&Xtb[(long)(d0 + dl) * SEQ + s0 + so] = u.v;
  }
  // Xb16[s][d]: straight cast, octet-swizzled within the 64-d block.
  if (Xb16 != nullptr) {
    __hip_bfloat16* Xcb = Xb16 + (long)b * SEQ * DIM;
#pragma unroll
    for (int it = 0; it < 2; ++it) {
      const int idx = it * 256 + tid;  // 0..511
      const int sl = idx >> 3;         // 0..63
      const int dc = idx & 7;          // source 8-wide d chunk
      const int dcs = dc ^ (sl & 7);   // swizzled destination octet
      union { short8 v; __hip_bfloat16 e[8]; } u;
#pragma unroll
      for (int j = 0; j < 8; ++j) u.e[j] = __float2bfloat16(tile[sl][dc * 8 + j]);
      *(short8*)&Xcb[(long)(s0 + sl) * DIM + d0 + dcs * 8] = u.v;
    }
  }
}

// ---------------- GEMM: C = A . Bt^T (2-phase, proven; k2 + k3 fallback) ----
template <int NSPLIT, bool AFP32, int SWZ, typename CT>
__global__ __launch_bounds__(256, 4) void gemm_bt_kernel(
    const float* __restrict__ Af, const __hip_bfloat16* __restrict__ Ab,
    const __hip_bfloat16* __restrict__ Bt, CT* __restrict__ C,
    int K, int lda, int ldb, int ldc, long strideA, long strideB, long strideC) {
  __shared__ __align__(16) __hip_bfloat16 As[2][BM * BK];  // [m][k]
  __shared__ __align__(16) __hip_bfloat16 Bs[2][BN * BK];  // [n][k]

  int bz, m0, n0;
  if constexpr (SWZ == 1) {
    const int lin = blockIdx.x;        // 0..127 per batch
    bz = blockIdx.z;
    const int xcd = lin & 7;
    const int t = lin >> 3;            // 0..15
    n0 = (t & 3) * BN;
    m0 = ((t >> 2) * 8 + xcd) * BM;
  } else if constexpr (SWZ == 2) {
    bz = blockIdx.x;                   // chunk id, fastest dim -> xcd = bz & 7
    int ti, tj;
    tri_map(blockIdx.y, ti, tj);       // upper triangle only
    m0 = ti * BM;
    n0 = tj * BN;
  } else {
    bz = blockIdx.z;
    m0 = blockIdx.y * BM;
    n0 = blockIdx.x * BN;
  }
  const int b = bz / NSPLIT;
  const int split = bz % NSPLIT;
  const int klen = K / NSPLIT;
  const int kb = split * klen;

  const int tid = threadIdx.x;
  const int w = tid >> 6;
  const int lane = tid & 63;
  const int r16 = lane & 15;
  const int kg = lane >> 4;
  const int wr = w >> 1;
  const int wc = w & 1;

  const float* Afb = AFP32 ? Af + b * strideA : nullptr;
  const __hip_bfloat16* Abb = AFP32 ? nullptr : Ab + b * strideA;
  const __hip_bfloat16* Btb = Bt + b * strideB;
  CT* Cb = C + (long)bz * strideC;

  const floatx4 vzero = {0.f, 0.f, 0.f, 0.f};
  floatx4 acc[4][4];
#pragma unroll
  for (int i = 0; i < 4; ++i)
#pragma unroll
    for (int j = 0; j < 4; ++j) acc[i][j] = vzero;

  const int arow = tid >> 1;
  const int ahalf = tid & 1;
  float f[16];

  auto stageB = [&](int buf, int k0) {
#pragma unroll
    for (int q = 0; q < 2; ++q) {
      const __hip_bfloat16* gb =
          Btb + (long)(n0 + w * 32 + q * 16 + (lane >> 2)) * ldb + k0 + (lane & 3) * 8;
      async_copy16(gb, &Bs[buf][(w * 32 + q * 16) * BK]);
    }
  };
  auto stageA = [&](int buf, int k0) {
#pragma unroll
    for (int q = 0; q < 2; ++q) {
      const __hip_bfloat16* ga =
          Abb + (long)(m0 + w * 32 + q * 16 + (lane >> 2)) * lda + k0 + (lane & 3) * 8;
      async_copy16(ga, &As[buf][(w * 32 + q * 16) * BK]);
    }
  };
  auto loadF = [&](int k0) {
    const float* ar = Afb + (long)(m0 + arow) * lda + k0 + ahalf * 16;
    *(float4*)(f + 0)  = *(const float4*)(ar + 0);
    *(float4*)(f + 4)  = *(const float4*)(ar + 4);
    *(float4*)(f + 8)  = *(const float4*)(ar + 8);
    *(float4*)(f + 12) = *(const float4*)(ar + 12);
  };
  auto writeF = [&](int buf) {
    union { short8 v[2]; __hip_bfloat16 e[16]; } u;
#pragma unroll
    for (int t = 0; t < 16; ++t) u.e[t] = __float2bfloat16(f[t]);
    short8* dst = (short8*)&As[buf][arow * BK + ahalf * 16];
    dst[0] = u.v[0];
    dst[1] = u.v[1];
  };

  const int nIter = klen / BK;
  if constexpr (AFP32) {
    loadF(kb);
    writeF(0);
    loadF(kb + BK);
  } else {
    stageA(0, kb);
  }
  stageB(0, kb);

  for (int t = 0; t < nIter; ++t) {
    const int cur = t & 1;
    __syncthreads();
    if (t + 1 < nIter) {
      if constexpr (AFP32) {
        writeF(cur ^ 1);
        if (t + 2 < nIter) loadF(kb + (t + 2) * BK);
      } else {
        stageA(cur ^ 1, kb + (t + 1) * BK);
      }
      stageB(cur ^ 1, kb + (t + 1) * BK);
    }

    short8 a[4], bfrag[4];
#pragma unroll
    for (int i = 0; i < 4; ++i)
      a[i] = *(const short8*)&As[cur][(wr * 64 + i * 16 + r16) * BK + kg * 8];
#pragma unroll
    for (int j = 0; j < 4; ++j)
      bfrag[j] = *(const short8*)&Bs[cur][(wc * 64 + j * 16 + r16) * BK + kg * 8];
#pragma unroll
    for (int i = 0; i < 4; ++i)
#pragma unroll
      for (int j = 0; j < 4; ++j)
        acc[i][j] = __builtin_amdgcn_mfma_f32_16x16x32_bf16(a[i], bfrag[j], acc[i][j], 0, 0, 0);
  }

#pragma unroll
  for (int i = 0; i < 4; ++i) {
    const int row_base = m0 + wr * 64 + i * 16 + kg * 4;
#pragma unroll
    for (int j = 0; j < 4; ++j) {
      const int col = n0 + wc * 64 + j * 16 + r16;
#pragma unroll
      for (int r = 0; r < 4; ++r) {
        const float v = acc[i][j][r];
        if constexpr (std::is_same<CT, float>::value)
          Cb[(long)(row_base + r) * ldc + col] = v;
        else
          Cb[(long)(row_base + r) * ldc + col] = __float2bfloat16(v);
      }
    }
  }
}

// ---------------- k3: 8-phase 256x256 GEMM, out = Xb16 . gram^T -------------
// Schedule ledger (NT=8 K-tiles of 64; iter J computes tiles 2J (buf0) and
// 2J+1 (buf1); one half-tile (2 gload_lds/thread) staged per phase):
//   ph1: T(2J+1).A0  ph2: T(2J+1).A1  ph3: T(2J+2).B0  ph4: T(2J+2).B1
//   ph5: T(2J+2).A0  ph6: T(2J+2).A1  ph7: T(2J+3).B0  ph8: T(2J+3).B1
// Slot-free proof: B-halves of a tile are last read at its first phase,
// A-halves at its 4th -> every stage above targets a freed slot.
// vmcnt gates (per-wave outstanding ledger): at ph4-end outstanding = 12
// (T2J+1.B[old 4] T2J+1.A[4] T2J+2.B[4]); need oldest 8 -> vmcnt(4).
// At ph8-end outstanding = 12 (T2J+2.B, T2J+2.A, T2J+3.B); need oldest 8
// -> vmcnt(4). Last iter: ph4 gate vmcnt(0) (tail drain), ph8 no gate.
// LDS reads conflict-free via octet-XOR baked into global content
// (k1's Xb16, kr's gram) -> linear gload_lds + XOR on ds_read (round-3
// measured: SQ_LDS_BANK_CONFLICT = 0).
#define VMCNT4() asm volatile("s_waitcnt vmcnt(4)" ::: "memory")
#define VMCNT0() asm volatile("s_waitcnt vmcnt(0)" ::: "memory")
#define BAR() asm volatile("s_barrier" ::: "memory")

__global__ __launch_bounds__(512, 2) void gemm_8ph_kernel(
    const __hip_bfloat16* __restrict__ Xs,  // swizzled Xb16 [B][S][D]
    const __hip_bfloat16* __restrict__ G,   // swizzled gram [B][D][D]
    float* __restrict__ C) {
  // A: [2][256][64] at 0, B: [2][256][64] at +32768 elems (128KB total)
  __shared__ __align__(16) __hip_bfloat16 smem[65536];
  __hip_bfloat16* Asm = smem;
  __hip_bfloat16* Bsm = smem + 32768;

  const int b  = blockIdx.x & 7;   // one batch per XCD (32 tiles = 32 CUs)
  const int tt = blockIdx.x >> 3;  // 0..31
  const int m0 = (tt >> 1) * 256;
  const int n0 = (tt & 1) * 256;

  const int tid = threadIdx.x;
  const int w = tid >> 6;          // 0..7
  const int lane = tid & 63;
  const int r16 = lane & 15;
  const int kg = lane >> 4;
  const int wm = w >> 2;           // 0..1 (M)
  const int wn = w & 3;            // 0..3 (N)
  const int ph = r16 & 7;

  const __hip_bfloat16* Xb = Xs + (long)b * SEQ * DIM;
  const __hip_bfloat16* Gb = G + (long)b * DIM * DIM;
  float* Cb = C + (long)b * SEQ * DIM;

  // half h (rows h*128..+128) of K-tile kt -> buf d. 2 rounds x 8KB.
  auto stgA = [&](int d, int h, int kt) {
#pragma unroll
    for (int R = 0; R < 2; ++R) {
      const int rt = h * 128 + R * 64 + w * 8;  // wave-uniform row base
      const __hip_bfloat16* g =
          Xb + (long)(m0 + rt + (lane >> 3)) * DIM + kt * 64 + (lane & 7) * 8;
      async_copy16(g, &Asm[d * 16384 + rt * 64]);
    }
  };
  auto stgB = [&](int d, int h, int kt) {
#pragma unroll
    for (int R = 0; R < 2; ++R) {
      const int rt = h * 128 + R * 64 + w * 8;
      const __hip_bfloat16* g =
          Gb + (long)(n0 + rt + (lane >> 3)) * DIM + kt * 64 + (lane & 7) * 8;
      async_copy16(g, &Bsm[d * 16384 + rt * 64]);
    }
  };

  const floatx4 vzero = {0.f, 0.f, 0.f, 0.f};
  floatx4 acc[8][4];
#pragma unroll
  for (int i = 0; i < 8; ++i)
#pragma unroll
    for (int j = 0; j < 4; ++j) acc[i][j] = vzero;

  short8 af[2][2], bf[4][2];

#define LDA8(q, d)                                                              \
  {                                                                             \
    _Pragma("unroll") for (int m2 = 0; m2 < 2; ++m2)                            \
    _Pragma("unroll") for (int ks = 0; ks < 2; ++ks)                            \
      af[m2][ks] = *(const short8*)&Asm[(d) * 16384 +                           \
          (wm * 128 + ((q) * 2 + m2) * 16 + r16) * 64 + (((ks * 4 + kg) ^ ph) * 8)]; \
  }
#define LDB8(d)                                                                 \
  {                                                                             \
    _Pragma("unroll") for (int nj = 0; nj < 4; ++nj)                            \
    _Pragma("unroll") for (int ks = 0; ks < 2; ++ks)                            \
      bf[nj][ks] = *(const short8*)&Bsm[(d) * 16384 +                           \
          (wn * 64 + nj * 16 + r16) * 64 + (((ks * 4 + kg) ^ ph) * 8)];         \
  }
#define MFMAQ(q)                                                                \
  {                                                                             \
    __builtin_amdgcn_s_setprio(1);                                              \
    _Pragma("unroll") for (int m2 = 0; m2 < 2; ++m2)                            \
    _Pragma("unroll") for (int nj = 0; nj < 4; ++nj)                            \
    _Pragma("unroll") for (int ks = 0; ks < 2; ++ks)                            \
      acc[(q) * 2 + m2][nj] = __builtin_amdgcn_mfma_f32_16x16x32_bf16(          \
          af[m2][ks], bf[nj][ks], acc[(q) * 2 + m2][nj], 0, 0, 0);              \
    __builtin_amdgcn_s_setprio(0);                                              \
  }

  // Prologue: T0 fully (B then A) + T1.B -> 12 loads; wait oldest 8 (=T0).
  stgB(0, 0, 0); stgB(0, 1, 0);
  stgA(0, 0, 0); stgA(0, 1, 0);
  stgB(1, 0, 1); stgB(1, 1, 1);
  VMCNT4();
  BAR();

  const int NI = DIM / 128;  // 4 iterations, 2 K-tiles each
  for (int J = 0; J < NI; ++J) {
    const int t0 = 2 * J;
    const bool g2 = (t0 + 2) < 8;   // stage tile t0+2?
    const bool g3 = (t0 + 3) < 8;   // stage tile t0+3?
    // ---- K-tile t0 (buf0) ----
    LDB8(0); LDA8(0, 0);
    stgA(1, 0, t0 + 1);
    BAR(); MFMAQ(0); BAR();

    LDA8(1, 0);
    stgA(1, 1, t0 + 1);
    BAR(); MFMAQ(1); BAR();

    LDA8(2, 0);
    if (g2) stgB(0, 0, t0 + 2);
    BAR(); MFMAQ(2); BAR();

    LDA8(3, 0);
    if (g2) stgB(0, 1, t0 + 2);
    BAR(); MFMAQ(3);
    if (J < NI - 1) { VMCNT4(); } else { VMCNT0(); }
    BAR();
    // ---- K-tile t0+1 (buf1) ----
    LDB8(1); LDA8(0, 1);
    if (g2) stgA(0, 0, t0 + 2);
    BAR(); MFMAQ(0); BAR();

    LDA8(1, 1);
    if (g2) stgA(0, 1, t0 + 2);
    BAR(); MFMAQ(1); BAR();

    LDA8(2, 1);
    if (g3) stgB(1, 0, t0 + 3);
    BAR(); MFMAQ(2); BAR();

    LDA8(3, 1);
    if (g3) stgB(1, 1, t0 + 3);
    BAR(); MFMAQ(3);
    if (J < NI - 1) { VMCNT4(); BAR(); }
  }

  // Epilogue: row = kg*4 + r, col = r16 (m89-verified C/D map)
#pragma unroll
  for (int mi = 0; mi < 8; ++mi) {
    const int row_base = m0 + wm * 128 + mi * 16 + kg * 4;
#pragma unroll
    for (int nj = 0; nj < 4; ++nj) {
      const int col = n0 + wn * 64 + nj * 16 + r16;
#pragma unroll
      for (int r = 0; r < 4; ++r)
        Cb[(long)(row_base + r) * DIM + col] = acc[mi][nj][r];
    }
  }
#undef LDA8
#undef LDB8
#undef MFMAQ
}

// ---------------- kr: reduce NSPLIT partials (triangle) -> full gram --------
// SWZG: store gram with octet-XOR (oct ^= row&7 per 64-col window) for the
// 8-phase k3; plain layout for the fallback path.
template <int NSPLIT, bool SWZG>
__global__ __launch_bounds__(256) void reduce_mirror_kernel(
    const __hip_bfloat16* __restrict__ P, __hip_bfloat16* __restrict__ G) {
  __shared__ float tile[64][65];
  int ti, tj;
  tri_map(blockIdx.x, ti, tj);
  const int b = blockIdx.y;
  const __hip_bfloat16* Pb = P + (long)b * NSPLIT * DIM * DIM;
  __hip_bfloat16* Gb = G + (long)b * DIM * DIM;
  const int r0 = ti * 128, c0 = tj * 128;
  const int tid = threadIdx.x;
  const int lrow = tid >> 3;        // 0..31
  const int lcol = (tid & 7) * 8;   // 0..56
  const int soct = SWZG ? (((tid & 7) ^ (lrow & 7)) * 8) : lcol;

#pragma unroll
  for (int q = 0; q < 4; ++q) {
    const int qr = (q >> 1) * 64, qc = (q & 1) * 64;
    float s[2][8];
#pragma unroll
    for (int h = 0; h < 2; ++h) {
      const int row = lrow + h * 32;
#pragma unroll
      for (int j = 0; j < 8; ++j) s[h][j] = 0.f;
#pragma unroll
      for (int p = 0; p < NSPLIT; ++p) {
        union { short8 v; __hip_bfloat16 e8[8]; } u;
        u.v = *(const short8*)&Pb[(long)p * DIM * DIM +
                                  (long)(r0 + qr + row) * DIM + c0 + qc + lcol];
#pragma unroll
        for (int j = 0; j < 8; ++j) s[h][j] += __bfloat162float(u.e8[j]);
      }
      union { short8 v; __hip_bfloat16 e8[8]; } o;
#pragma unroll
      for (int j = 0; j < 8; ++j) o.e8[j] = __float2bfloat16(s[h][j]);
      // (row&7) == (lrow&7): r0,qr,h*32 all ≡ 0 mod 8
      *(short8*)&Gb[(long)(r0 + qr + row) * DIM + c0 + qc + soct] = o.v;
    }
    if (ti != tj) {
      if (q) __syncthreads();
#pragma unroll
      for (int h = 0; h < 2; ++h) {
        const int row = lrow + h * 32;
#pragma unroll
        for (int j = 0; j < 8; ++j) tile[row][lcol + j] = s[h][j];
      }
      __syncthreads();
#pragma unroll
      for (int it = 0; it < 2; ++it) {
        const int idx = it * 256 + tid;
        const int dl = idx >> 3;          // mirror row offset (0..63)
        const int so = (idx & 7) * 8;     // mirror col chunk
        const int soct2 = SWZG ? (((idx & 7) ^ (dl & 7)) * 8) : so;
        union { short8 v; __hip_bfloat16 e8[8]; } o;
#pragma unroll
        for (int j = 0; j < 8; ++j) o.e8[j] = __float2bfloat16(tile[so + j][dl]);
        *(short8*)&Gb[(long)(c0 + qc + dl) * DIM + r0 + qr + soct2] = o.v;
      }
    }
  }
}

// ---------------- host launch ----------------------------------------------
extern "C" void kernel_launch(void* const* d_in, const int* in_sizes, int n_in,
                              void* d_out, int out_size, void* d_ws, size_t ws_size,
                              hipStream_t stream) {
  const float* X = (const float*)d_in[0];
  float* out = (float*)d_out;
  const long xtBytes = (long)BATCH * DIM * SEQ * 2;               // 33.5 MB
  const long gramBytes = (long)BATCH * DIM * DIM * 2;             // 4.2 MB
  const long partBytes = (long)BATCH * SPLITK * DIM * DIM * 2;    // 33.5 MB (bf16)
  __hip_bfloat16* Xt = (__hip_bfloat16*)d_out;
  __hip_bfloat16* gram = (__hip_bfloat16*)d_ws;

  const bool bigWs = ws_size >= (size_t)(gramBytes + xtBytes + partBytes);
  const bool midWs = ws_size >= (size_t)(gramBytes + xtBytes);
  __hip_bfloat16* Xb16 = midWs ? (__hip_bfloat16*)((char*)d_ws + gramBytes) : nullptr;

  // k1: Xt[b][d][s] (+ swizzled Xb16[b][s][d] if ws fits)
  transpose_cast_kernel<<<dim3(SEQ / 64, DIM / 64, BATCH), 256, 0, stream>>>(X, Xt, Xb16);

  // k2: split-8 gram partials (bf16), upper-triangle tiles only (symmetry)
  __hip_bfloat16* partials = bigWs
      ? (__hip_bfloat16*)((char*)d_ws + gramBytes + xtBytes)
      : (__hip_bfloat16*)((char*)d_out + xtBytes);
  gemm_bt_kernel<SPLITK, false, 2, __hip_bfloat16>
      <<<dim3(BATCH * SPLITK, 10, 1), 256, 0, stream>>>(
          nullptr, Xt, Xt, partials, SEQ, SEQ, SEQ, DIM,
          (long)DIM * SEQ, (long)DIM * SEQ, (long)DIM * DIM);

  // kr: triangle partials -> full gram (mirror off-diagonal tiles)
  if (midWs) {
    reduce_mirror_kernel<SPLITK, true><<<dim3(10, BATCH), 256, 0, stream>>>(
        partials, gram);
    // k3: 8-phase 256^2, one batch per XCD, 256 blocks = 1/CU
    gemm_8ph_kernel<<<dim3(256, 1, 1), 512, 0, stream>>>(Xb16, gram, out);
  } else {
    reduce_mirror_kernel<SPLITK, false><<<dim3(10, BATCH), 256, 0, stream>>>(
        partials, gram);
    gemm_bt_kernel<1, true, 1, float><<<dim3(128, 1, BATCH), 256, 0, stream>>>(
        X, nullptr, gram, out, DIM, DIM, DIM, DIM,
        (long)SEQ * DIM, (long)DIM * DIM, (long)SEQ * DIM);
  }
}

// Round 5
// 162.535 us; speedup vs baseline: 1.1440x; 1.0042x over previous
//
#include <hip/hip_runtime.h>
#include <hip/hip_bf16.h>
#include <type_traits>

// out[b] = X[b] @ (X[b]^T @ X[b]);  B=8, S=4096, D=512, fp32 in/out.
// Pipeline (bf16 MFMA, fp32 accumulate), ws = 268MB observed:
//   k1: Xt[d][s] bf16 -> d_out[0:33.5M) ; Xb16[s][d] bf16 (octet-swizzled
//       per 64-d window: oct ^= s&7) -> ws+4.2M
//   k2: split-K=8 gram partials bf16, upper-triangle tiles only (symmetry),
//       XCD-swizzled, LDS dbuf (proven 2-phase gemm_bt) -> ws+37.7M
//   kr: reduce 8 bf16 partials -> full bf16 gram via LDS-transpose mirror;
//       gram stored octet-swizzled (oct ^= row&7 per 64-col window) for k3.
//   k3: 8-phase 256^2 deep-pipelined GEMM (T3+T4 counted vmcnt, T5 setprio).
//       Round-5 fix: phase boundaries pinned (lgkmcnt(0)+sched_barrier(0)
//       after opening s_barrier, sched_barrier(0) before closing s_barrier) —
//       the barrier asm alone does NOT order register-only MFMAs (rule #18
//       mechanism), so without pinning the compiler can dissolve the
//       8-phase interleave that T3's gain depends on.

typedef __attribute__((ext_vector_type(8))) short short8;
typedef __attribute__((ext_vector_type(4))) float floatx4;

#define BM 128
#define BN 128
#define BK 32

#define BATCH 8
#define SEQ 4096
#define DIM 512
#define SPLITK 8

__device__ __forceinline__ void async_copy16(const __hip_bfloat16* g, __hip_bfloat16* l) {
  __builtin_amdgcn_global_load_lds((const __attribute__((address_space(1))) void*)g,
                                   (__attribute__((address_space(3))) void*)l, 16, 0, 0);
}

// Upper-triangle tile map: t in [0,10) -> (ti<=tj) of a 4x4 tile grid.
__device__ __forceinline__ void tri_map(int t, int& ti, int& tj) {
  if (t < 4)      { ti = 0; tj = t; }
  else if (t < 7) { ti = 1; tj = t - 3; }
  else if (t < 9) { ti = 2; tj = t - 5; }
  else            { ti = 3; tj = 3; }
}

// ---------------- k1: transpose+cast (Xt) and swizzled straight cast (Xb16) -
__global__ __launch_bounds__(256) void transpose_cast_kernel(
    const float* __restrict__ X, __hip_bfloat16* __restrict__ Xt,
    __hip_bfloat16* __restrict__ Xb16) {
  __shared__ float tile[64][65];
  const int b = blockIdx.z;
  const int s0 = blockIdx.x * 64;
  const int d0 = blockIdx.y * 64;
  const int tid = threadIdx.x;
  const float* Xb = X + (long)b * SEQ * DIM;
  __hip_bfloat16* Xtb = Xt + (long)b * DIM * SEQ;
  {
    const int c4 = (tid & 15) * 4;
    const int r0 = tid >> 4;  // 0..15
#pragma unroll
    for (int r = 0; r < 64; r += 16) {
      const float4 v = *(const float4*)&Xb[(long)(s0 + r + r0) * DIM + d0 + c4];
      tile[r + r0][c4 + 0] = v.x;
      tile[r + r0][c4 + 1] = v.y;
      tile[r + r0][c4 + 2] = v.z;
      tile[r + r0][c4 + 3] = v.w;
    }
  }
  __syncthreads();
  // Xt[d][s]: pack 8 consecutive s per 16B store.
#pragma unroll
  for (int it = 0; it < 2; ++it) {
    const int idx = it * 256 + tid;    // 0..511
    const int dl = idx >> 3;           // 0..63
    const int so = (idx & 7) * 8;      // 0,8,..,56
    union { short8 v; __hip_bfloat16 e[8]; } u;
#pragma unroll
    for (int j = 0; j < 8; ++j) u.e[j] = __float2bfloat16(tile[so + j][dl]);
    *(short8*)&Xtb[(long)(d0 + dl) * SEQ + s0 + so] = u.v;
  }
  // Xb16[s][d]: straight cast, octet-swizzled within the 64-d block.
  if (Xb16 != nullptr) {
    __hip_bfloat16* Xcb = Xb16 + (long)b * SEQ * DIM;
#pragma unroll
    for (int it = 0; it < 2; ++it) {
      const int idx = it * 256 + tid;  // 0..511
      const int sl = idx >> 3;         // 0..63
      const int dc = idx & 7;          // source 8-wide d chunk
      const int dcs = dc ^ (sl & 7);   // swizzled destination octet
      union { short8 v; __hip_bfloat16 e[8]; } u;
#pragma unroll
      for (int j = 0; j < 8; ++j) u.e[j] = __float2bfloat16(tile[sl][dc * 8 + j]);
      *(short8*)&Xcb[(long)(s0 + sl) * DIM + d0 + dcs * 8] = u.v;
    }
  }
}

// ---------------- GEMM: C = A . Bt^T (2-phase, proven; k2 + k3 fallback) ----
template <int NSPLIT, bool AFP32, int SWZ, typename CT>
__global__ __launch_bounds__(256, 4) void gemm_bt_kernel(
    const float* __restrict__ Af, const __hip_bfloat16* __restrict__ Ab,
    const __hip_bfloat16* __restrict__ Bt, CT* __restrict__ C,
    int K, int lda, int ldb, int ldc, long strideA, long strideB, long strideC) {
  __shared__ __align__(16) __hip_bfloat16 As[2][BM * BK];  // [m][k]
  __shared__ __align__(16) __hip_bfloat16 Bs[2][BN * BK];  // [n][k]

  int bz, m0, n0;
  if constexpr (SWZ == 1) {
    const int lin = blockIdx.x;        // 0..127 per batch
    bz = blockIdx.z;
    const int xcd = lin & 7;
    const int t = lin >> 3;            // 0..15
    n0 = (t & 3) * BN;
    m0 = ((t >> 2) * 8 + xcd) * BM;
  } else if constexpr (SWZ == 2) {
    bz = blockIdx.x;                   // chunk id, fastest dim -> xcd = bz & 7
    int ti, tj;
    tri_map(blockIdx.y, ti, tj);       // upper triangle only
    m0 = ti * BM;
    n0 = tj * BN;
  } else {
    bz = blockIdx.z;
    m0 = blockIdx.y * BM;
    n0 = blockIdx.x * BN;
  }
  const int b = bz / NSPLIT;
  const int split = bz % NSPLIT;
  const int klen = K / NSPLIT;
  const int kb = split * klen;

  const int tid = threadIdx.x;
  const int w = tid >> 6;
  const int lane = tid & 63;
  const int r16 = lane & 15;
  const int kg = lane >> 4;
  const int wr = w >> 1;
  const int wc = w & 1;

  const float* Afb = AFP32 ? Af + b * strideA : nullptr;
  const __hip_bfloat16* Abb = AFP32 ? nullptr : Ab + b * strideA;
  const __hip_bfloat16* Btb = Bt + b * strideB;
  CT* Cb = C + (long)bz * strideC;

  const floatx4 vzero = {0.f, 0.f, 0.f, 0.f};
  floatx4 acc[4][4];
#pragma unroll
  for (int i = 0; i < 4; ++i)
#pragma unroll
    for (int j = 0; j < 4; ++j) acc[i][j] = vzero;

  const int arow = tid >> 1;
  const int ahalf = tid & 1;
  float f[16];

  auto stageB = [&](int buf, int k0) {
#pragma unroll
    for (int q = 0; q < 2; ++q) {
      const __hip_bfloat16* gb =
          Btb + (long)(n0 + w * 32 + q * 16 + (lane >> 2)) * ldb + k0 + (lane & 3) * 8;
      async_copy16(gb, &Bs[buf][(w * 32 + q * 16) * BK]);
    }
  };
  auto stageA = [&](int buf, int k0) {
#pragma unroll
    for (int q = 0; q < 2; ++q) {
      const __hip_bfloat16* ga =
          Abb + (long)(m0 + w * 32 + q * 16 + (lane >> 2)) * lda + k0 + (lane & 3) * 8;
      async_copy16(ga, &As[buf][(w * 32 + q * 16) * BK]);
    }
  };
  auto loadF = [&](int k0) {
    const float* ar = Afb + (long)(m0 + arow) * lda + k0 + ahalf * 16;
    *(float4*)(f + 0)  = *(const float4*)(ar + 0);
    *(float4*)(f + 4)  = *(const float4*)(ar + 4);
    *(float4*)(f + 8)  = *(const float4*)(ar + 8);
    *(float4*)(f + 12) = *(const float4*)(ar + 12);
  };
  auto writeF = [&](int buf) {
    union { short8 v[2]; __hip_bfloat16 e[16]; } u;
#pragma unroll
    for (int t = 0; t < 16; ++t) u.e[t] = __float2bfloat16(f[t]);
    short8* dst = (short8*)&As[buf][arow * BK + ahalf * 16];
    dst[0] = u.v[0];
    dst[1] = u.v[1];
  };

  const int nIter = klen / BK;
  if constexpr (AFP32) {
    loadF(kb);
    writeF(0);
    loadF(kb + BK);
  } else {
    stageA(0, kb);
  }
  stageB(0, kb);

  for (int t = 0; t < nIter; ++t) {
    const int cur = t & 1;
    __syncthreads();
    if (t + 1 < nIter) {
      if constexpr (AFP32) {
        writeF(cur ^ 1);
        if (t + 2 < nIter) loadF(kb + (t + 2) * BK);
      } else {
        stageA(cur ^ 1, kb + (t + 1) * BK);
      }
      stageB(cur ^ 1, kb + (t + 1) * BK);
    }

    short8 a[4], bfrag[4];
#pragma unroll
    for (int i = 0; i < 4; ++i)
      a[i] = *(const short8*)&As[cur][(wr * 64 + i * 16 + r16) * BK + kg * 8];
#pragma unroll
    for (int j = 0; j < 4; ++j)
      bfrag[j] = *(const short8*)&Bs[cur][(wc * 64 + j * 16 + r16) * BK + kg * 8];
#pragma unroll
    for (int i = 0; i < 4; ++i)
#pragma unroll
      for (int j = 0; j < 4; ++j)
        acc[i][j] = __builtin_amdgcn_mfma_f32_16x16x32_bf16(a[i], bfrag[j], acc[i][j], 0, 0, 0);
  }

#pragma unroll
  for (int i = 0; i < 4; ++i) {
    const int row_base = m0 + wr * 64 + i * 16 + kg * 4;
#pragma unroll
    for (int j = 0; j < 4; ++j) {
      const int col = n0 + wc * 64 + j * 16 + r16;
#pragma unroll
      for (int r = 0; r < 4; ++r) {
        const float v = acc[i][j][r];
        if constexpr (std::is_same<CT, float>::value)
          Cb[(long)(row_base + r) * ldc + col] = v;
        else
          Cb[(long)(row_base + r) * ldc + col] = __float2bfloat16(v);
      }
    }
  }
}

// ---------------- k3: 8-phase 256x256 GEMM, out = Xb16 . gram^T -------------
// Schedule ledger (NT=8 K-tiles of 64; iter J computes tiles 2J (buf0) and
// 2J+1 (buf1); one half-tile (2 gload_lds/thread) staged per phase):
//   ph1: T(2J+1).A0  ph2: T(2J+1).A1  ph3: T(2J+2).B0  ph4: T(2J+2).B1
//   ph5: T(2J+2).A0  ph6: T(2J+2).A1  ph7: T(2J+3).B0  ph8: T(2J+3).B1
// vmcnt gates at ph4/ph8 only (counted, never 0 mid-loop): outstanding = 12,
// oldest 8 must land -> vmcnt(4). Last iter: ph4 gates vmcnt(0), ph8 none.
// Phase pinning: opening s_barrier -> s_waitcnt lgkmcnt(0) -> sched_barrier(0)
// -> setprio(1) MFMA setprio(0) -> sched_barrier(0) -> [gate] -> s_barrier.
// LDS reads conflict-free via octet-XOR baked into global content (k1/kr),
// round-3 measured SQ_LDS_BANK_CONFLICT = 0.
#define VMCNT4() asm volatile("s_waitcnt vmcnt(4)" ::: "memory")
#define VMCNT0() asm volatile("s_waitcnt vmcnt(0)" ::: "memory")
#define BAR() asm volatile("s_barrier" ::: "memory")
#define OPEN_PIN()                                         \
  do {                                                     \
    asm volatile("s_waitcnt lgkmcnt(0)" ::: "memory");     \
    __builtin_amdgcn_sched_barrier(0);                     \
  } while (0)
#define CLOSE_PIN() __builtin_amdgcn_sched_barrier(0)

__global__ __launch_bounds__(512, 2) void gemm_8ph_kernel(
    const __hip_bfloat16* __restrict__ Xs,  // swizzled Xb16 [B][S][D]
    const __hip_bfloat16* __restrict__ G,   // swizzled gram [B][D][D]
    float* __restrict__ C) {
  // A: [2][256][64] at 0, B: [2][256][64] at +32768 elems (128KB total)
  __shared__ __align__(16) __hip_bfloat16 smem[65536];
  __hip_bfloat16* Asm = smem;
  __hip_bfloat16* Bsm = smem + 32768;

  const int b  = blockIdx.x & 7;   // one batch per XCD (32 tiles = 32 CUs)
  const int tt = blockIdx.x >> 3;  // 0..31
  const int m0 = (tt >> 1) * 256;
  const int n0 = (tt & 1) * 256;

  const int tid = threadIdx.x;
  const int w = tid >> 6;          // 0..7
  const int lane = tid & 63;
  const int r16 = lane & 15;
  const int kg = lane >> 4;
  const int wm = w >> 2;           // 0..1 (M)
  const int wn = w & 3;            // 0..3 (N)
  const int ph = r16 & 7;

  const __hip_bfloat16* Xb = Xs + (long)b * SEQ * DIM;
  const __hip_bfloat16* Gb = G + (long)b * DIM * DIM;
  float* Cb = C + (long)b * SEQ * DIM;

  // half h (rows h*128..+128) of K-tile kt -> buf d. 2 rounds x 8KB.
  auto stgA = [&](int d, int h, int kt) {
#pragma unroll
    for (int R = 0; R < 2; ++R) {
      const int rt = h * 128 + R * 64 + w * 8;  // wave-uniform row base
      const __hip_bfloat16* g =
          Xb + (long)(m0 + rt + (lane >> 3)) * DIM + kt * 64 + (lane & 7) * 8;
      async_copy16(g, &Asm[d * 16384 + rt * 64]);
    }
  };
  auto stgB = [&](int d, int h, int kt) {
#pragma unroll
    for (int R = 0; R < 2; ++R) {
      const int rt = h * 128 + R * 64 + w * 8;
      const __hip_bfloat16* g =
          Gb + (long)(n0 + rt + (lane >> 3)) * DIM + kt * 64 + (lane & 7) * 8;
      async_copy16(g, &Bsm[d * 16384 + rt * 64]);
    }
  };

  const floatx4 vzero = {0.f, 0.f, 0.f, 0.f};
  floatx4 acc[8][4];
#pragma unroll
  for (int i = 0; i < 8; ++i)
#pragma unroll
    for (int j = 0; j < 4; ++j) acc[i][j] = vzero;

  short8 af[2][2], bf[4][2];

#define LDA8(q, d)                                                              \
  {                                                                             \
    _Pragma("unroll") for (int m2 = 0; m2 < 2; ++m2)                            \
    _Pragma("unroll") for (int ks = 0; ks < 2; ++ks)                            \
      af[m2][ks] = *(const short8*)&Asm[(d) * 16384 +                           \
          (wm * 128 + ((q) * 2 + m2) * 16 + r16) * 64 + (((ks * 4 + kg) ^ ph) * 8)]; \
  }
#define LDB8(d)                                                                 \
  {                                                                             \
    _Pragma("unroll") for (int nj = 0; nj < 4; ++nj)                            \
    _Pragma("unroll") for (int ks = 0; ks < 2; ++ks)                            \
      bf[nj][ks] = *(const short8*)&Bsm[(d) * 16384 +                           \
          (wn * 64 + nj * 16 + r16) * 64 + (((ks * 4 + kg) ^ ph) * 8)];         \
  }
#define MFMAQ(q)                                                                \
  {                                                                             \
    __builtin_amdgcn_s_setprio(1);                                              \
    _Pragma("unroll") for (int m2 = 0; m2 < 2; ++m2)                            \
    _Pragma("unroll") for (int nj = 0; nj < 4; ++nj)                            \
    _Pragma("unroll") for (int ks = 0; ks < 2; ++ks)                            \
      acc[(q) * 2 + m2][nj] = __builtin_amdgcn_mfma_f32_16x16x32_bf16(          \
          af[m2][ks], bf[nj][ks], acc[(q) * 2 + m2][nj], 0, 0, 0);              \
    __builtin_amdgcn_s_setprio(0);                                              \
  }

  // Prologue: T0 fully (B then A) + T1.B -> 12 loads; wait oldest 8 (=T0).
  stgB(0, 0, 0); stgB(0, 1, 0);
  stgA(0, 0, 0); stgA(0, 1, 0);
  stgB(1, 0, 1); stgB(1, 1, 1);
  VMCNT4();
  BAR();

  const int NI = DIM / 128;  // 4 iterations, 2 K-tiles each
#pragma unroll
  for (int J = 0; J < NI; ++J) {
    const int t0 = 2 * J;
    const bool g2 = (t0 + 2) < 8;   // stage tile t0+2? (constant after unroll)
    const bool g3 = (t0 + 3) < 8;   // stage tile t0+3?
    // ---- K-tile t0 (buf0) ----
    LDB8(0); LDA8(0, 0);
    stgA(1, 0, t0 + 1);
    BAR(); OPEN_PIN(); MFMAQ(0); CLOSE_PIN(); BAR();

    LDA8(1, 0);
    stgA(1, 1, t0 + 1);
    BAR(); OPEN_PIN(); MFMAQ(1); CLOSE_PIN(); BAR();

    LDA8(2, 0);
    if (g2) stgB(0, 0, t0 + 2);
    BAR(); OPEN_PIN(); MFMAQ(2); CLOSE_PIN(); BAR();

    LDA8(3, 0);
    if (g2) stgB(0, 1, t0 + 2);
    BAR(); OPEN_PIN(); MFMAQ(3); CLOSE_PIN();
    if (J < NI - 1) { VMCNT4(); } else { VMCNT0(); }
    BAR();
    // ---- K-tile t0+1 (buf1) ----
    LDB8(1); LDA8(0, 1);
    if (g2) stgA(0, 0, t0 + 2);
    BAR(); OPEN_PIN(); MFMAQ(0); CLOSE_PIN(); BAR();

    LDA8(1, 1);
    if (g2) stgA(0, 1, t0 + 2);
    BAR(); OPEN_PIN(); MFMAQ(1); CLOSE_PIN(); BAR();

    LDA8(2, 1);
    if (g3) stgB(1, 0, t0 + 3);
    BAR(); OPEN_PIN(); MFMAQ(2); CLOSE_PIN(); BAR();

    LDA8(3, 1);
    if (g3) stgB(1, 1, t0 + 3);
    BAR(); OPEN_PIN(); MFMAQ(3); CLOSE_PIN();
    if (J < NI - 1) { VMCNT4(); BAR(); }
  }

  // Epilogue: row = kg*4 + r, col = r16 (m89-verified C/D map)
#pragma unroll
  for (int mi = 0; mi < 8; ++mi) {
    const int row_base = m0 + wm * 128 + mi * 16 + kg * 4;
#pragma unroll
    for (int nj = 0; nj < 4; ++nj) {
      const int col = n0 + wn * 64 + nj * 16 + r16;
#pragma unroll
      for (int r = 0; r < 4; ++r)
        Cb[(long)(row_base + r) * DIM + col] = acc[mi][nj][r];
    }
  }
#undef LDA8
#undef LDB8
#undef MFMAQ
}

// ---------------- kr: reduce NSPLIT partials (triangle) -> full gram --------
// SWZG: store gram with octet-XOR (oct ^= row&7 per 64-col window) for the
// 8-phase k3; plain layout for the fallback path.
template <int NSPLIT, bool SWZG>
__global__ __launch_bounds__(256) void reduce_mirror_kernel(
    const __hip_bfloat16* __restrict__ P, __hip_bfloat16* __restrict__ G) {
  __shared__ float tile[64][65];
  int ti, tj;
  tri_map(blockIdx.x, ti, tj);
  const int b = blockIdx.y;
  const __hip_bfloat16* Pb = P + (long)b * NSPLIT * DIM * DIM;
  __hip_bfloat16* Gb = G + (long)b * DIM * DIM;
  const int r0 = ti * 128, c0 = tj * 128;
  const int tid = threadIdx.x;
  const int lrow = tid >> 3;        // 0..31
  const int lcol = (tid & 7) * 8;   // 0..56
  const int soct = SWZG ? (((tid & 7) ^ (lrow & 7)) * 8) : lcol;

#pragma unroll
  for (int q = 0; q < 4; ++q) {
    const int qr = (q >> 1) * 64, qc = (q & 1) * 64;
    float s[2][8];
#pragma unroll
    for (int h = 0; h < 2; ++h) {
      const int row = lrow + h * 32;
#pragma unroll
      for (int j = 0; j < 8; ++j) s[h][j] = 0.f;
#pragma unroll
      for (int p = 0; p < NSPLIT; ++p) {
        union { short8 v; __hip_bfloat16 e8[8]; } u;
        u.v = *(const short8*)&Pb[(long)p * DIM * DIM +
                                  (long)(r0 + qr + row) * DIM + c0 + qc + lcol];
#pragma unroll
        for (int j = 0; j < 8; ++j) s[h][j] += __bfloat162float(u.e8[j]);
      }
      union { short8 v; __hip_bfloat16 e8[8]; } o;
#pragma unroll
      for (int j = 0; j < 8; ++j) o.e8[j] = __float2bfloat16(s[h][j]);
      // (row&7) == (lrow&7): r0,qr,h*32 all = 0 mod 8
      *(short8*)&Gb[(long)(r0 + qr + row) * DIM + c0 + qc + soct] = o.v;
    }
    if (ti != tj) {
      if (q) __syncthreads();
#pragma unroll
      for (int h = 0; h < 2; ++h) {
        const int row = lrow + h * 32;
#pragma unroll
        for (int j = 0; j < 8; ++j) tile[row][lcol + j] = s[h][j];
      }
      __syncthreads();
#pragma unroll
      for (int it = 0; it < 2; ++it) {
        const int idx = it * 256 + tid;
        const int dl = idx >> 3;          // mirror row offset (0..63)
        const int so = (idx & 7) * 8;     // mirror col chunk
        const int soct2 = SWZG ? (((idx & 7) ^ (dl & 7)) * 8) : so;
        union { short8 v; __hip_bfloat16 e8[8]; } o;
#pragma unroll
        for (int j = 0; j < 8; ++j) o.e8[j] = __float2bfloat16(tile[so + j][dl]);
        *(short8*)&Gb[(long)(c0 + qc + dl) * DIM + r0 + qr + soct2] = o.v;
      }
    }
  }
}

// ---------------- host launch ----------------------------------------------
extern "C" void kernel_launch(void* const* d_in, const int* in_sizes, int n_in,
                              void* d_out, int out_size, void* d_ws, size_t ws_size,
                              hipStream_t stream) {
  const float* X = (const float*)d_in[0];
  float* out = (float*)d_out;
  const long xtBytes = (long)BATCH * DIM * SEQ * 2;               // 33.5 MB
  const long gramBytes = (long)BATCH * DIM * DIM * 2;             // 4.2 MB
  const long partBytes = (long)BATCH * SPLITK * DIM * DIM * 2;    // 33.5 MB (bf16)
  __hip_bfloat16* Xt = (__hip_bfloat16*)d_out;
  __hip_bfloat16* gram = (__hip_bfloat16*)d_ws;

  const bool bigWs = ws_size >= (size_t)(gramBytes + xtBytes + partBytes);
  const bool midWs = ws_size >= (size_t)(gramBytes + xtBytes);
  __hip_bfloat16* Xb16 = midWs ? (__hip_bfloat16*)((char*)d_ws + gramBytes) : nullptr;

  // k1: Xt[b][d][s] (+ swizzled Xb16[b][s][d] if ws fits)
  transpose_cast_kernel<<<dim3(SEQ / 64, DIM / 64, BATCH), 256, 0, stream>>>(X, Xt, Xb16);

  // k2: split-8 gram partials (bf16), upper-triangle tiles only (symmetry)
  __hip_bfloat16* partials = bigWs
      ? (__hip_bfloat16*)((char*)d_ws + gramBytes + xtBytes)
      : (__hip_bfloat16*)((char*)d_out + xtBytes);
  gemm_bt_kernel<SPLITK, false, 2, __hip_bfloat16>
      <<<dim3(BATCH * SPLITK, 10, 1), 256, 0, stream>>>(
          nullptr, Xt, Xt, partials, SEQ, SEQ, SEQ, DIM,
          (long)DIM * SEQ, (long)DIM * SEQ, (long)DIM * DIM);

  // kr: triangle partials -> full gram (mirror off-diagonal tiles)
  if (midWs) {
    reduce_mirror_kernel<SPLITK, true><<<dim3(10, BATCH), 256, 0, stream>>>(
        partials, gram);
    // k3: 8-phase 256^2, one batch per XCD, 256 blocks = 1/CU
    gemm_8ph_kernel<<<dim3(256, 1, 1), 512, 0, stream>>>(Xb16, gram, out);
  } else {
    reduce_mirror_kernel<SPLITK, false><<<dim3(10, BATCH), 256, 0, stream>>>(
        partials, gram);
    gemm_bt_kernel<1, true, 1, float><<<dim3(128, 1, BATCH), 256, 0, stream>>>(
        X, nullptr, gram, out, DIM, DIM, DIM, DIM,
        (long)SEQ * DIM, (long)DIM * DIM, (long)SEQ * DIM);
  }
}